// Round 11
// baseline (22.184 us; speedup 1.0000x reference)
//
#include <hip/hip_runtime.h>

// FeatureViewEncoder: per-feature Conv1d(1,H,3) + mask + max-over-time.
// out[b,f,h] = max_{l: mask[b,l]!=0} ( sum_k x[b,l+k,f]*w[f,h,k] + bias[f,h] ), else -1e9.
//
// R11 = R6 structure at 2x occupancy (the one untried mechanism-matched lever):
//  - FG=4, grid=2048 -> 8 blocks/CU (LDS 13.9KB), __launch_bounds__(256,8)
//    caps VGPR at 64 (est. ~55 used) -> 8 waves/SIMD vs R6's 4.
//  - wave = 1f x 16h x 4l, HPT=8 (R6's proven low register pressure).
//    All 64 lanes read the same xc row: 4 distinct 16B quads per b128,
//    16-lane same-address broadcast -> conflict-free.
//  - atomic-free compaction: per-wave ballot + wave-count prefix (2 barriers
//    before phase B instead of 3, no atomic serialization).
// Rationale: kernel time is insensitive to VALU/LDS instruction counts
// (R6 vs R7/R9/R10); the ~4us above the 2.6us VALU floor is latency slack,
// which occupancy attacks directly.

#define NEG_INF_F (-1e9f)

typedef float v2f __attribute__((ext_vector_type(2)));

constexpr int B_ = 128;
constexpr int V_ = 200;
constexpr int F_ = 64;
constexpr int H_ = 128;
constexpr int L_ = V_ - 3 + 1;   // 198

constexpr int NTHR = 256;
constexpr int FG   = 4;                    // features per block (1 per wave)
constexpr int HPT  = 8;                    // h-outputs per thread (4 packed pairs)
constexpr int MAXW = (L_ + 7) & ~7;        // 200: max windows, mult of 8
constexpr int WSTR = 4 * MAXW + 16;        // 816 floats, 16B-aligned rows

__global__ __launch_bounds__(NTHR, 8)
void fve_kernel(const float* __restrict__ x,     // [B,V,F]
                const int*   __restrict__ mask,  // [B,1,L]
                const float* __restrict__ w,     // [F,H,K]
                const float* __restrict__ bias,  // [F,H]
                float* __restrict__ out)         // [B,F,H]
{
    __shared__ __align__(16) float xc[FG][WSTR];  // compacted windows: xc[f][4j+k]
    __shared__ int vlist[MAXW];
    __shared__ int wcount[4];

    const int b    = blockIdx.x >> 4;      // grid = B * (F/FG) = 2048
    const int f0   = (blockIdx.x & 15) * FG;
    const int t    = threadIdx.x;
    const int wave = t >> 6;               // 0..3
    const int lane = t & 63;

    // Phase A: atomic-free ballot compaction (order irrelevant for max).
    {
        const bool valid = (t < L_) && (mask[b * L_ + t] != 0);
        const unsigned long long bal = __ballot(valid);
        if (lane == 0) wcount[wave] = (int)__popcll(bal);
        __syncthreads();
        int base = 0;
#pragma unroll
        for (int ww = 0; ww < 4; ++ww)
            if (ww < wave) base += wcount[ww];
        if (valid) {
            const int pos = base + (int)__popcll(bal & ((1ull << lane) - 1ull));
            vlist[pos] = t;
        }
    }
    __syncthreads();

    const int n    = wcount[0] + wcount[1] + wcount[2] + wcount[3];
    const int npad = (n + 7) & ~7;   // mult of 8 (dup window 0; max idempotent)

    // Phase B: build stride-4 windows straight from global:
    //   xc[c][4j+k] = x[b, l_j+k, f0+c], k=0..2 (slot 3 = don't-care pad).
    // item = j*4 + k ; k==3 lanes idle (25% of this short phase only).
    for (int item = t; item < npad * 4; item += NTHR) {
        const int j = item >> 2;
        const int k = item & 3;
        if (k == 3) continue;
        const int l = (j < n) ? vlist[j] : vlist[0];
        const float4 g = *reinterpret_cast<const float4*>(
            x + ((size_t)b * V_ + l + k) * F_ + f0);
        const int col = 4 * j + k;
        xc[0][col] = g.x;
        xc[1][col] = g.y;
        xc[2][col] = g.z;
        xc[3][col] = g.w;
    }
    __syncthreads();

    // Thread map (main loop): wave = 1 f-row x 16 h-lanes x 4 l-lanes.
    const int h_lane = (lane >> 2) & 15;   // 0..15
    const int l_lane = lane & 3;           // 0..3
    const int f      = f0 + wave;
    const int h0     = h_lane * HPT;       // 0,8,...,120

    // Weights for h0..h0+7 repacked into h-pairs (memory layout [h][k]).
    const float* wp = w + ((size_t)f * H_ + h0) * 3;
    float wt[24];
#pragma unroll
    for (int j = 0; j < 6; ++j)
        *reinterpret_cast<float4*>(&wt[j * 4]) =
            *reinterpret_cast<const float4*>(wp + j * 4);

    float bsc[8];
    *reinterpret_cast<float4*>(&bsc[0]) =
        *reinterpret_cast<const float4*>(bias + (size_t)f * H_ + h0);
    *reinterpret_cast<float4*>(&bsc[4]) =
        *reinterpret_cast<const float4*>(bias + (size_t)f * H_ + h0 + 4);

    v2f wp0[4], wp1[4], wp2[4], bpk[4], mpk[4];
#pragma unroll
    for (int p = 0; p < 4; ++p) {
        wp0[p] = (v2f){wt[6 * p + 0], wt[6 * p + 3]};
        wp1[p] = (v2f){wt[6 * p + 1], wt[6 * p + 4]};
        wp2[p] = (v2f){wt[6 * p + 2], wt[6 * p + 5]};
        bpk[p] = (v2f){bsc[2 * p], bsc[2 * p + 1]};
        mpk[p] = (v2f){NEG_INF_F, NEG_INF_F};
    }

    const float4* xq = reinterpret_cast<const float4*>(&xc[wave][0]);

#define PROCQ(Q)                                                              \
    do {                                                                      \
        const v2f X0 = (v2f){(Q).x, (Q).x};                                   \
        const v2f X1 = (v2f){(Q).y, (Q).y};                                   \
        const v2f X2 = (v2f){(Q).z, (Q).z};                                   \
        _Pragma("unroll")                                                     \
        for (int p = 0; p < 4; ++p) {                                         \
            const v2f c = __builtin_elementwise_fma(X0, wp0[p],               \
                          __builtin_elementwise_fma(X1, wp1[p],               \
                          __builtin_elementwise_fma(X2, wp2[p], bpk[p])));    \
            mpk[p] = __builtin_elementwise_max(mpk[p], c);                    \
        }                                                                     \
    } while (0)

    // Main loop: 1 conflict-free ds_read_b128 per window; lane handles
    // windows l_lane, l_lane+4, ...; 2 reads batched per 8-window step.
    for (int u = 0; u < npad; u += 8) {
        const int i0 = u + l_lane;
        const float4 q0 = xq[i0];
        const float4 q1 = xq[i0 + 4];
        PROCQ(q0);
        PROCQ(q1);
    }
#undef PROCQ

    // Reduce across the 4 l-lanes (same (f,h0)).
#pragma unroll
    for (int p = 0; p < 4; ++p) {
        float a = __shfl_xor(mpk[p].x, 1, 64);
        float c = __shfl_xor(mpk[p].y, 1, 64);
        mpk[p].x = fmaxf(mpk[p].x, a);
        mpk[p].y = fmaxf(mpk[p].y, c);
        a = __shfl_xor(mpk[p].x, 2, 64);
        c = __shfl_xor(mpk[p].y, 2, 64);
        mpk[p].x = fmaxf(mpk[p].x, a);
        mpk[p].y = fmaxf(mpk[p].y, c);
    }

    // l_lane 0 writes h0..h0+3, l_lane 1 writes h0+4..h0+7 (float4 each).
    if (l_lane < 2) {
        float* op = out + ((size_t)b * F_ + f) * H_ + h0 + l_lane * 4;
        const int pb = l_lane * 2;
        *reinterpret_cast<float4*>(op) =
            make_float4(mpk[pb].x, mpk[pb].y, mpk[pb + 1].x, mpk[pb + 1].y);
    }
}

extern "C" void kernel_launch(void* const* d_in, const int* in_sizes, int n_in,
                              void* d_out, int out_size, void* d_ws, size_t ws_size,
                              hipStream_t stream) {
    const float* x    = (const float*)d_in[0];  // input_visit
    const int*   mask = (const int*)d_in[1];    // visit_mask
    const float* w    = (const float*)d_in[2];  // conv_w
    const float* bias = (const float*)d_in[3];  // conv_b
    float* out = (float*)d_out;

    const int grid = B_ * (F_ / FG);  // 2048
    fve_kernel<<<grid, NTHR, 0, stream>>>(x, mask, w, bias, out);
}

// Round 12
// 16.219 us; speedup vs baseline: 1.3678x; 1.3678x over previous
//
#include <hip/hip_runtime.h>

// FeatureViewEncoder: per-feature Conv1d(1,H,3) + mask + max-over-time.
// out[b,f,h] = max_{l: mask[b,l]!=0} ( sum_k x[b,l+k,f]*w[f,h,k] + bias[f,h] ), else -1e9.
//
// FINAL (= R6, the empirical optimum over 11 rounds of probing):
//  - compacted WINDOW buffer in LDS: one ds_read_b128 yields a full
//    (x0,x1,x2) conv window -> branch-free inner loop over valid l only.
//  - wave = 2f x 16h x 2l, HPT=8: low register pressure, 4 blocks/CU.
//  - packed v_pk_fma_f32 / v_pk_max_f32 on h-pairs.
//  - grid 1024, single launch (each extra graph node costs ~3-4us).
// Probed and rejected: branches instead of compaction (R2 +7us), HPT=16
// in all register/occupancy configs (R7/R9/R10 +1.6-2.1us), 8 blocks/CU
// (R11 +6us), 2 blocks/CU (R7), split launches (R8 +3.9us).
// Measured composition: ~5.4us harness + ~4us launch/ramp + ~6.9us kernel
// (VALU floor ~2.6us); remaining slack is latency insensitive to structure.

#define NEG_INF_F (-1e9f)

typedef float v2f __attribute__((ext_vector_type(2)));

constexpr int B_ = 128;
constexpr int V_ = 200;
constexpr int F_ = 64;
constexpr int H_ = 128;
constexpr int L_ = V_ - 3 + 1;   // 198

constexpr int NTHR = 256;
constexpr int FG   = 8;                    // features per block
constexpr int HPT  = 8;                    // h-outputs per thread (4 packed pairs)
constexpr int MAXW = (L_ + 7) & ~7;        // 200: max windows, mult of 8
constexpr int WSTR = 4 * MAXW + 8;         // 808 floats: 808%32==8 -> f-rows 8 banks apart

__global__ __launch_bounds__(NTHR)
void fve_kernel(const float* __restrict__ x,     // [B,V,F]
                const int*   __restrict__ mask,  // [B,1,L]
                const float* __restrict__ w,     // [F,H,K]
                const float* __restrict__ bias,  // [F,H]
                float* __restrict__ out)         // [B,F,H]
{
    __shared__ __align__(16) float xc[FG][WSTR];  // compacted windows: xc[f][4j+k]
    __shared__ int vlist[L_];
    __shared__ int vcnt;

    const int b  = blockIdx.x >> 3;        // grid = B * (F/FG) = 1024
    const int f0 = (blockIdx.x & 7) * FG;
    const int t  = threadIdx.x;

    if (t == 0) vcnt = 0;
    __syncthreads();

    // Phase A: compact valid time-steps (order irrelevant for max).
    if (t < L_ && mask[b * L_ + t] != 0) {
        const int p = atomicAdd(&vcnt, 1);
        vlist[p] = t;
    }
    __syncthreads();

    const int n    = vcnt;
    const int npad = (n + 7) & ~7;   // mult of 8 (dup window 0; max is idempotent)

    // Phase B: build stride-4 windows straight from global:
    //   xc[fq*4+c][4j+k] = x[b, l_j+k, f0+fq*4+c],  k=0..2 (slot 3 = don't-care pad).
    // item = j*8 + k*2 + half ; k==3 lanes idle (25% of phase B only).
    for (int item = t; item < npad * 8; item += NTHR) {
        const int j    = item >> 3;
        const int k    = (item >> 1) & 3;
        const int half = item & 1;
        if (k == 3) continue;
        const int l = (j < n) ? vlist[j] : vlist[0];
        const float4 g = *reinterpret_cast<const float4*>(
            x + ((size_t)b * V_ + l + k) * F_ + f0 + half * 4);
        const int col = 4 * j + k;
        xc[half * 4 + 0][col] = g.x;
        xc[half * 4 + 1][col] = g.y;
        xc[half * 4 + 2][col] = g.z;
        xc[half * 4 + 3][col] = g.w;
    }
    __syncthreads();

    // Thread map: wave covers 2 f-rows; 16 h-lanes x 2 l-lanes per f.
    const int f_local = t >> 5;            // 0..7
    const int f       = f0 + f_local;
    const int h_lane  = (t >> 1) & 15;
    const int h0      = h_lane * HPT;      // 0,8,...,120
    const int l_lane  = t & 1;

    // Weights for h0..h0+7 repacked into h-pairs (layout in mem: [h][k]).
    const float* wp = w + ((size_t)f * H_ + h0) * 3;
    float wt[24];
#pragma unroll
    for (int j = 0; j < 6; ++j)
        *reinterpret_cast<float4*>(&wt[j * 4]) =
            *reinterpret_cast<const float4*>(wp + j * 4);

    float bsc[8];
    *reinterpret_cast<float4*>(&bsc[0]) =
        *reinterpret_cast<const float4*>(bias + (size_t)f * H_ + h0);
    *reinterpret_cast<float4*>(&bsc[4]) =
        *reinterpret_cast<const float4*>(bias + (size_t)f * H_ + h0 + 4);

    v2f wp0[4], wp1[4], wp2[4], bpk[4], mpk[4];
#pragma unroll
    for (int p = 0; p < 4; ++p) {
        wp0[p] = (v2f){wt[6 * p + 0], wt[6 * p + 3]};
        wp1[p] = (v2f){wt[6 * p + 1], wt[6 * p + 4]};
        wp2[p] = (v2f){wt[6 * p + 2], wt[6 * p + 5]};
        bpk[p] = (v2f){bsc[2 * p], bsc[2 * p + 1]};
        mpk[p] = (v2f){NEG_INF_F, NEG_INF_F};
    }

    const float4* xq = reinterpret_cast<const float4*>(&xc[f_local][0]);

#define PROCQ(Q)                                                              \
    do {                                                                      \
        const v2f X0 = (v2f){(Q).x, (Q).x};                                   \
        const v2f X1 = (v2f){(Q).y, (Q).y};                                   \
        const v2f X2 = (v2f){(Q).z, (Q).z};                                   \
        _Pragma("unroll")                                                     \
        for (int p = 0; p < 4; ++p) {                                         \
            const v2f c = __builtin_elementwise_fma(X0, wp0[p],               \
                          __builtin_elementwise_fma(X1, wp1[p],               \
                          __builtin_elementwise_fma(X2, wp2[p], bpk[p])));    \
            mpk[p] = __builtin_elementwise_max(mpk[p], c);                    \
        }                                                                     \
    } while (0)

    // Inner loop: 1 ds_read_b128 per window; lane handles windows l_lane, +2, +4...
    // npad % 8 == 0 -> per-lane trip count % 4 == 0: clean 4x unroll, loads batched.
    for (int u = 0; u < npad; u += 8) {
        const int i0 = u + l_lane;
        const float4 q0 = xq[i0];
        const float4 q1 = xq[i0 + 2];
        const float4 q2 = xq[i0 + 4];
        const float4 q3 = xq[i0 + 6];
        PROCQ(q0);
        PROCQ(q1);
        PROCQ(q2);
        PROCQ(q3);
    }
#undef PROCQ

    // Reduce across the l_lane pair (lanes t, t^1 hold same (f,h0)).
#pragma unroll
    for (int p = 0; p < 4; ++p) {
        const float a = __shfl_xor(mpk[p].x, 1, 64);
        const float c = __shfl_xor(mpk[p].y, 1, 64);
        mpk[p].x = fmaxf(mpk[p].x, a);
        mpk[p].y = fmaxf(mpk[p].y, c);
    }

    // Each lane writes one float4: l_lane 0 -> h0..h0+3, l_lane 1 -> h0+4..h0+7.
    float* op = out + ((size_t)b * F_ + f) * H_ + h0 + l_lane * 4;
    const int pb = l_lane * 2;
    *reinterpret_cast<float4*>(op) =
        make_float4(mpk[pb].x, mpk[pb].y, mpk[pb + 1].x, mpk[pb + 1].y);
}

extern "C" void kernel_launch(void* const* d_in, const int* in_sizes, int n_in,
                              void* d_out, int out_size, void* d_ws, size_t ws_size,
                              hipStream_t stream) {
    const float* x    = (const float*)d_in[0];  // input_visit
    const int*   mask = (const int*)d_in[1];    // visit_mask
    const float* w    = (const float*)d_in[2];  // conv_w
    const float* bias = (const float*)d_in[3];  // conv_b
    float* out = (float*)d_out;

    const int grid = B_ * (F_ / FG);  // 1024
    fve_kernel<<<grid, NTHR, 0, stream>>>(x, mask, w, bias, out);
}